// Round 7
// baseline (224.312 us; speedup 1.0000x reference)
//
#include <hip/hip_runtime.h>
#include <hip/hip_bf16.h>
#include <stdint.h>

#define N_NODES 50000
#define N_EDGES 1000000
#define HIDDEN 128

using short8  = __attribute__((ext_vector_type(8))) short;
using floatx4 = __attribute__((ext_vector_type(4))) float;

__device__ __forceinline__ float bf2f(uint16_t u) {
    return __uint_as_float(((uint32_t)u) << 16);
}
__device__ __forceinline__ uint16_t f2bf(float f) {
    uint32_t x = __float_as_uint(f);
    return (uint16_t)((x + 0x7FFFu + ((x >> 16) & 1u)) >> 16);
}
__device__ __forceinline__ uint32_t cvt_pk_bf16(float lo, float hi) {
    uint32_t r;
    asm("v_cvt_pk_bf16_f32 %0, %1, %2" : "=v"(r) : "v"(lo), "v"(hi));
    return r;
}
__device__ __forceinline__ float fast_silu(float x) {
    float e = __expf(-x);
    return x * __builtin_amdgcn_rcpf(1.0f + e);
}

// ---------------------------------------------------------------------------
// Kernel 1: At[n][k] = sum_j h[n][j]*W1[j][k] + b1[k]   (k<128)
//           Bt[n][k] = sum_j h[n][j]*W1[128+j][k]
// ---------------------------------------------------------------------------
__global__ __launch_bounds__(256) void precompute_AB(
    const float* __restrict__ h, const float* __restrict__ W1,
    const float* __restrict__ b1,
    uint16_t* __restrict__ At, uint16_t* __restrict__ Bt)
{
    __shared__ uint16_t w1t[256 * 128];  // [c][j] bf16, XOR-swizzled, 64 KB
    int t = threadIdx.x;
    for (int idx = t; idx < 256 * 128; idx += 256) {
        int c = idx >> 7, j = idx & 127;
        float v = (c < 128) ? W1[j * 128 + c] : W1[(128 + j) * 128 + (c - 128)];
        int byte_off = (c << 8) + (j << 1);
        byte_off ^= ((c & 7) << 4);
        *(uint16_t*)((char*)w1t + byte_off) = f2bf(v);
    }
    __syncthreads();

    int wave = t >> 6, lane = t & 63;
    int lrow = lane & 15, kg = lane >> 4;

    for (int g = 0; g < 2; ++g) {
        int nodeBase = blockIdx.x * 128 + g * 64 + wave * 16;
        if (nodeBase >= N_NODES) break;
        int node = nodeBase + lrow;
        int nclamp = node < N_NODES ? node : N_NODES - 1;
        const float* hrow = h + (size_t)nclamp * 128;

        short8 afrag[4];
#pragma unroll
        for (int kk = 0; kk < 4; ++kk) {
            int k0 = kk * 32 + kg * 8;
            float4 f0 = *(const float4*)(hrow + k0);
            float4 f1 = *(const float4*)(hrow + k0 + 4);
            short8 a;
            uint32_t* ap = (uint32_t*)&a;
            ap[0] = cvt_pk_bf16(f0.x, f0.y);
            ap[1] = cvt_pk_bf16(f0.z, f0.w);
            ap[2] = cvt_pk_bf16(f1.x, f1.y);
            ap[3] = cvt_pk_bf16(f1.z, f1.w);
            afrag[kk] = a;
        }

        for (int nt = 0; nt < 16; ++nt) {
            floatx4 acc = {0.f, 0.f, 0.f, 0.f};
            int c = nt * 16 + lrow;
#pragma unroll
            for (int kk = 0; kk < 4; ++kk) {
                int byte_off = (c << 8) + ((kk * 32 + kg * 8) << 1);
                byte_off ^= ((c & 7) << 4);
                short8 b = *(const short8*)((const char*)w1t + byte_off);
                acc = __builtin_amdgcn_mfma_f32_16x16x32_bf16(afrag[kk], b, acc, 0, 0, 0);
            }
#pragma unroll
            for (int r = 0; r < 4; ++r) {
                int onode = nodeBase + kg * 4 + r;
                if (onode < N_NODES) {
                    float v = acc[r];
                    if (c < 128) {
                        At[(size_t)onode * 128 + c] = f2bf(v + b1[c]);
                    } else {
                        Bt[(size_t)onode * 128 + (c - 128)] = f2bf(v);
                    }
                }
            }
        }
    }
}

// ---------------------------------------------------------------------------
// Kernel 2 helpers
// ---------------------------------------------------------------------------
__device__ __forceinline__ void gather_rows(const uint16_t* __restrict__ ar,
                                            const uint16_t* __restrict__ br,
                                            int kg, short8 ga[4], short8 gb[4]) {
#pragma unroll
    for (int kk = 0; kk < 4; ++kk) {
        int k0 = kk * 32 + kg * 8;
        ga[kk] = *(const short8*)(ar + k0);
        gb[kk] = *(const short8*)(br + k0);
    }
}

__device__ __forceinline__ void layer1_silu(const short8 ga[4], const short8 gb[4],
                                            float attr, const float* s_w1e, int kg,
                                            short8 afrag[4]) {
#pragma unroll
    for (int kk = 0; kk < 4; ++kk) {
        int k0 = kk * 32 + kg * 8;
        float4 w0 = *(const float4*)(&s_w1e[k0]);
        float4 w1 = *(const float4*)(&s_w1e[k0 + 4]);
        float xs[8];
        xs[0] = fast_silu(bf2f((uint16_t)ga[kk][0]) + bf2f((uint16_t)gb[kk][0]) + attr * w0.x);
        xs[1] = fast_silu(bf2f((uint16_t)ga[kk][1]) + bf2f((uint16_t)gb[kk][1]) + attr * w0.y);
        xs[2] = fast_silu(bf2f((uint16_t)ga[kk][2]) + bf2f((uint16_t)gb[kk][2]) + attr * w0.z);
        xs[3] = fast_silu(bf2f((uint16_t)ga[kk][3]) + bf2f((uint16_t)gb[kk][3]) + attr * w0.w);
        xs[4] = fast_silu(bf2f((uint16_t)ga[kk][4]) + bf2f((uint16_t)gb[kk][4]) + attr * w1.x);
        xs[5] = fast_silu(bf2f((uint16_t)ga[kk][5]) + bf2f((uint16_t)gb[kk][5]) + attr * w1.y);
        xs[6] = fast_silu(bf2f((uint16_t)ga[kk][6]) + bf2f((uint16_t)gb[kk][6]) + attr * w1.z);
        xs[7] = fast_silu(bf2f((uint16_t)ga[kk][7]) + bf2f((uint16_t)gb[kk][7]) + attr * w1.w);
        uint32_t* up = (uint32_t*)&afrag[kk];
        up[0] = cvt_pk_bf16(xs[0], xs[1]);
        up[1] = cvt_pk_bf16(xs[2], xs[3]);
        up[2] = cvt_pk_bf16(xs[4], xs[5]);
        up[3] = cvt_pk_bf16(xs[6], xs[7]);
    }
}

// ---------------------------------------------------------------------------
// Kernel 2: per-edge fused MLP. 512-thr blocks, one wave = 32 edges.
// Schedule per pair: gather(h0) -> layer1(h0) -> gather(h1) [flies under
// h0's layer-2] -> layer2+epi(h0) -> layer1(h1) -> layer2+epi(h1).
// Peak gather liveness = ONE 32-reg batch (fits the 64-80 VGPR allocation;
// round-5's both-batches-up-front needed 64 live regs and got fragmented).
// Plain __launch_bounds__(512): rounds 2/3/6 showed both directions of
// register-count forcing (spill OR cap) are hazards.
// ---------------------------------------------------------------------------
__global__ __launch_bounds__(512) void edge_kernel(
    const int* __restrict__ rowIdx, const int* __restrict__ colIdx,
    const float* __restrict__ edge_attr, const float* __restrict__ edge_mask,
    const float* __restrict__ coord_diff,
    const float* __restrict__ W1, const float* __restrict__ W2,
    const float* __restrict__ b2, const float* __restrict__ W3,
    const uint16_t* __restrict__ At, const uint16_t* __restrict__ Bt,
    float* __restrict__ agg)
{
    __shared__ uint16_t w2t[128 * 128];  // [n][k] bf16, XOR-swizzled, 32 KB
    __shared__ float s_w1e[128], s_b2[128], s_w3[128];
    int t = threadIdx.x;
    for (int idx = t; idx < 128 * 128; idx += 512) {
        int n = idx >> 7, k = idx & 127;
        float v = W2[k * 128 + n];
        int byte_off = (n << 8) + (k << 1);
        byte_off ^= ((n & 7) << 4);
        *(uint16_t*)((char*)w2t + byte_off) = f2bf(v);
    }
    if (t < 128) { s_w1e[t] = W1[256 * 128 + t]; s_b2[t] = b2[t]; s_w3[t] = W3[t]; }
    __syncthreads();

    int wave = t >> 6, lane = t & 63;
    int lrow = lane & 15, kg = lane >> 4;

    const int numPairs = N_EDGES / 32;           // 31250
    int wavesTotal = gridDim.x * 8;
    int waveId = blockIdx.x * 8 + wave;

    for (int pair = waveId; pair < numPairs; pair += wavesTotal) {
        int ebase0 = pair * 32;
        int ebase1 = ebase0 + 16;
        int e0 = ebase0 + lrow;
        int e1 = ebase1 + lrow;
        int r0 = rowIdx[e0], c0 = colIdx[e0];
        int r1 = rowIdx[e1], c1 = colIdx[e1];
        float attr0 = edge_attr[e0];
        float attr1 = edge_attr[e1];

        // ---- gather half-0, run layer-1 on it ----
        short8 ga[4], gb[4];
        gather_rows(At + (size_t)r0 * 128, Bt + (size_t)c0 * 128, kg, ga, gb);
        short8 afrag0[4];
        layer1_silu(ga, gb, attr0, s_w1e, kg, afrag0);

        // ---- issue half-1 gathers (regs freed by layer1-h0); they fly
        //      under half-0's layer-2 ----
        gather_rows(At + (size_t)r1 * 128, Bt + (size_t)c1 * 128, kg, ga, gb);

#pragma unroll
        for (int half = 0; half < 2; ++half) {
            int ebase = half ? ebase1 : ebase0;
            short8 afrag[4];
            if (half == 0) {
                afrag[0] = afrag0[0]; afrag[1] = afrag0[1];
                afrag[2] = afrag0[2]; afrag[3] = afrag0[3];
            } else {
                layer1_silu(ga, gb, attr1, s_w1e, kg, afrag);
            }

            // ---- layer 2 + fused silu + W3 dot (b2 folded into C) ----
            float pm0 = 0.f, pm1 = 0.f, pm2 = 0.f, pm3 = 0.f;
#pragma unroll
            for (int nt = 0; nt < 8; ++nt) {
                int n = nt * 16 + lrow;
                float b2v = s_b2[n];
                floatx4 acc = {b2v, b2v, b2v, b2v};
#pragma unroll
                for (int kk = 0; kk < 4; ++kk) {
                    int byte_off = (n << 8) + ((kk * 32 + kg * 8) << 1);
                    byte_off ^= ((n & 7) << 4);
                    short8 b = *(const short8*)((const char*)w2t + byte_off);
                    acc = __builtin_amdgcn_mfma_f32_16x16x32_bf16(afrag[kk], b, acc, 0, 0, 0);
                }
                float w3v = s_w3[n];
                pm0 += fast_silu(acc[0]) * w3v;
                pm1 += fast_silu(acc[1]) * w3v;
                pm2 += fast_silu(acc[2]) * w3v;
                pm3 += fast_silu(acc[3]) * w3v;
            }

            // reduce across the 16 lanes of each group
#pragma unroll
            for (int m = 1; m < 16; m <<= 1) {
                pm0 += __shfl_xor(pm0, m, 64);
                pm1 += __shfl_xor(pm1, m, 64);
                pm2 += __shfl_xor(pm2, m, 64);
                pm3 += __shfl_xor(pm3, m, 64);
            }
            // group kg holds m for edges ebase + kg*4 + {0..3} in pm0..pm3

            if (lrow < 12) {
                int rsel = lrow / 3;
                int dim = lrow - rsel * 3;
                float mval = (rsel == 0) ? pm0 : (rsel == 1) ? pm1
                           : (rsel == 2) ? pm2 : pm3;
                int eg = ebase + kg * 4 + rsel;
                float val = coord_diff[eg * 3 + dim] * mval * edge_mask[eg];
                int rnode = rowIdx[eg];
                atomicAdd(&agg[rnode * 3 + dim], val);
            }
        }
    }
}

// ---------------------------------------------------------------------------
// Kernel 3: out = (coord + agg/100) * node_mask
// ---------------------------------------------------------------------------
__global__ __launch_bounds__(256) void finalize_kernel(
    const float* __restrict__ coord, const float* __restrict__ agg,
    const float* __restrict__ node_mask, float* __restrict__ out)
{
    int i = blockIdx.x * 256 + threadIdx.x;
    if (i < N_NODES * 3) {
        out[i] = (coord[i] + agg[i] * 0.01f) * node_mask[i / 3];
    }
}

extern "C" void kernel_launch(void* const* d_in, const int* in_sizes, int n_in,
                              void* d_out, int out_size, void* d_ws, size_t ws_size,
                              hipStream_t stream) {
    const float* h          = (const float*)d_in[0];
    const float* coord      = (const float*)d_in[1];
    const int*   eidx       = (const int*)d_in[2];   // [2][N_EDGES] int32
    const float* coord_diff = (const float*)d_in[3];
    const float* edge_attr  = (const float*)d_in[4];
    const float* node_mask  = (const float*)d_in[5];
    const float* edge_mask  = (const float*)d_in[6];
    const float* W1 = (const float*)d_in[7];
    const float* b1 = (const float*)d_in[8];
    const float* W2 = (const float*)d_in[9];
    const float* b2 = (const float*)d_in[10];
    const float* W3 = (const float*)d_in[11];
    float* out = (float*)d_out;

    uint16_t* At = (uint16_t*)d_ws;                        // 12.8 MB
    uint16_t* Bt = At + (size_t)N_NODES * 128;             // 12.8 MB
    float*   agg = (float*)(Bt + (size_t)N_NODES * 128);   // 600 KB

    hipMemsetAsync(agg, 0, N_NODES * 3 * sizeof(float), stream);

    precompute_AB<<<(N_NODES + 127) / 128, 256, 0, stream>>>(h, W1, b1, At, Bt);

    edge_kernel<<<1024, 512, 0, stream>>>(eidx, eidx + N_EDGES, edge_attr, edge_mask,
                                          coord_diff, W1, W2, b2, W3, At, Bt, agg);

    finalize_kernel<<<(N_NODES * 3 + 255) / 256, 256, 0, stream>>>(coord, agg, node_mask, out);
}

// Round 8
// 178.449 us; speedup vs baseline: 1.2570x; 1.2570x over previous
//
#include <hip/hip_runtime.h>
#include <hip/hip_bf16.h>
#include <stdint.h>

#define N_NODES 50000
#define N_EDGES 1000000
#define HIDDEN 128

using short8  = __attribute__((ext_vector_type(8))) short;
using floatx4 = __attribute__((ext_vector_type(4))) float;
using floatx2 = __attribute__((ext_vector_type(2))) float;

__device__ __forceinline__ float bf2f(uint16_t u) {
    return __uint_as_float(((uint32_t)u) << 16);
}
__device__ __forceinline__ uint16_t f2bf(float f) {
    uint32_t x = __float_as_uint(f);
    return (uint16_t)((x + 0x7FFFu + ((x >> 16) & 1u)) >> 16);
}
__device__ __forceinline__ uint32_t cvt_pk_bf16(float lo, float hi) {
    uint32_t r;
    asm("v_cvt_pk_bf16_f32 %0, %1, %2" : "=v"(r) : "v"(lo), "v"(hi));
    return r;
}
__device__ __forceinline__ float fast_silu(float x) {
    float e = __expf(-x);
    return x * __builtin_amdgcn_rcpf(1.0f + e);
}
// one f32 -> one fp8 e4m3 byte (gfx950 OCP format)
__device__ __forceinline__ uint8_t f2fp8(float v) {
    uint32_t p = __builtin_amdgcn_cvt_pk_fp8_f32(v, v, 0u, false);
    return (uint8_t)(p & 0xffu);
}
// unpack 8 fp8 bytes (two u32 words) -> 8 f32
__device__ __forceinline__ void fp8_unpack8(uint32_t w0, uint32_t w1, float f[8]) {
    floatx2 p;
    p = __builtin_amdgcn_cvt_pk_f32_fp8(w0, false); f[0] = p[0]; f[1] = p[1];
    p = __builtin_amdgcn_cvt_pk_f32_fp8(w0, true);  f[2] = p[0]; f[3] = p[1];
    p = __builtin_amdgcn_cvt_pk_f32_fp8(w1, false); f[4] = p[0]; f[5] = p[1];
    p = __builtin_amdgcn_cvt_pk_f32_fp8(w1, true);  f[6] = p[0]; f[7] = p[1];
}

// channel permutation for At/Bt storage: c = kk*32 + kg*8 + j  ->  kg*32 + kk*8 + j
// (so one lane's 4 MFMA k-runs are 32 contiguous bytes: 2 x 16B loads)
__device__ __forceinline__ int perm_c(int c) {
    return ((c >> 3) & 3) * 32 + ((c >> 5) << 3) + (c & 7);
}

// ---------------------------------------------------------------------------
// Kernel 1: At[n][k] = sum_j h[n][j]*W1[j][k] + b1[k]   (k<128)  -> fp8
//           Bt[n][k] = sum_j h[n][j]*W1[128+j][k]                -> fp8
// stored with perm_c channel order.
// ---------------------------------------------------------------------------
__global__ __launch_bounds__(256) void precompute_AB(
    const float* __restrict__ h, const float* __restrict__ W1,
    const float* __restrict__ b1,
    uint8_t* __restrict__ At, uint8_t* __restrict__ Bt)
{
    __shared__ uint16_t w1t[256 * 128];  // [c][j] bf16, XOR-swizzled, 64 KB
    int t = threadIdx.x;
    for (int idx = t; idx < 256 * 128; idx += 256) {
        int c = idx >> 7, j = idx & 127;
        float v = (c < 128) ? W1[j * 128 + c] : W1[(128 + j) * 128 + (c - 128)];
        int byte_off = (c << 8) + (j << 1);
        byte_off ^= ((c & 7) << 4);
        *(uint16_t*)((char*)w1t + byte_off) = f2bf(v);
    }
    __syncthreads();

    int wave = t >> 6, lane = t & 63;
    int lrow = lane & 15, kg = lane >> 4;

    for (int g = 0; g < 2; ++g) {
        int nodeBase = blockIdx.x * 128 + g * 64 + wave * 16;
        if (nodeBase >= N_NODES) break;
        int node = nodeBase + lrow;
        int nclamp = node < N_NODES ? node : N_NODES - 1;
        const float* hrow = h + (size_t)nclamp * 128;

        short8 afrag[4];
#pragma unroll
        for (int kk = 0; kk < 4; ++kk) {
            int k0 = kk * 32 + kg * 8;
            float4 f0 = *(const float4*)(hrow + k0);
            float4 f1 = *(const float4*)(hrow + k0 + 4);
            short8 a;
            uint32_t* ap = (uint32_t*)&a;
            ap[0] = cvt_pk_bf16(f0.x, f0.y);
            ap[1] = cvt_pk_bf16(f0.z, f0.w);
            ap[2] = cvt_pk_bf16(f1.x, f1.y);
            ap[3] = cvt_pk_bf16(f1.z, f1.w);
            afrag[kk] = a;
        }

        for (int nt = 0; nt < 16; ++nt) {
            floatx4 acc = {0.f, 0.f, 0.f, 0.f};
            int c = nt * 16 + lrow;
#pragma unroll
            for (int kk = 0; kk < 4; ++kk) {
                int byte_off = (c << 8) + ((kk * 32 + kg * 8) << 1);
                byte_off ^= ((c & 7) << 4);
                short8 b = *(const short8*)((const char*)w1t + byte_off);
                acc = __builtin_amdgcn_mfma_f32_16x16x32_bf16(afrag[kk], b, acc, 0, 0, 0);
            }
#pragma unroll
            for (int r = 0; r < 4; ++r) {
                int onode = nodeBase + kg * 4 + r;
                if (onode < N_NODES) {
                    float v = acc[r];
                    if (c < 128) {
                        At[(size_t)onode * 128 + perm_c(c)] = f2fp8(v + b1[c]);
                    } else {
                        int cc = c - 128;
                        Bt[(size_t)onode * 128 + perm_c(cc)] = f2fp8(v);
                    }
                }
            }
        }
    }
}

// ---------------------------------------------------------------------------
// Kernel 2: per-edge fused MLP. 512-thr blocks, one wave = 32 edges (two
// 16-edge tiles). Round-5 structure (VGPR must stay <=64: 8 waves/SIMD;
// crossing 64 halves occupancy - round-7 regression). fp8 gathers: both
// halves' A/B rows = 8 x 16B loads, 32 dest regs total, all in flight
// before any compute.
// ---------------------------------------------------------------------------
__global__ __launch_bounds__(512) void edge_kernel(
    const int* __restrict__ rowIdx, const int* __restrict__ colIdx,
    const float* __restrict__ edge_attr, const float* __restrict__ edge_mask,
    const float* __restrict__ coord_diff,
    const float* __restrict__ W1, const float* __restrict__ W2,
    const float* __restrict__ b2, const float* __restrict__ W3,
    const uint8_t* __restrict__ At, const uint8_t* __restrict__ Bt,
    float* __restrict__ agg)
{
    __shared__ uint16_t w2t[128 * 128];  // [n][k] bf16, XOR-swizzled, 32 KB
    __shared__ float s_w1e[128], s_b2[128], s_w3[128];
    int t = threadIdx.x;
    for (int idx = t; idx < 128 * 128; idx += 512) {
        int n = idx >> 7, k = idx & 127;
        float v = W2[k * 128 + n];
        int byte_off = (n << 8) + (k << 1);
        byte_off ^= ((n & 7) << 4);
        *(uint16_t*)((char*)w2t + byte_off) = f2bf(v);
    }
    if (t < 128) { s_w1e[t] = W1[256 * 128 + t]; s_b2[t] = b2[t]; s_w3[t] = W3[t]; }
    __syncthreads();

    int wave = t >> 6, lane = t & 63;
    int lrow = lane & 15, kg = lane >> 4;

    const int numPairs = N_EDGES / 32;           // 31250
    int wavesTotal = gridDim.x * 8;
    int waveId = blockIdx.x * 8 + wave;

    for (int pair = waveId; pair < numPairs; pair += wavesTotal) {
        int ebase0 = pair * 32;
        int ebase1 = ebase0 + 16;
        int e0 = ebase0 + lrow;
        int e1 = ebase1 + lrow;
        int r0 = rowIdx[e0], c0 = colIdx[e0];
        int r1 = rowIdx[e1], c1 = colIdx[e1];
        float attr0 = edge_attr[e0];
        float attr1 = edge_attr[e1];

        // ---- all 8 gathers up front (half-0 first) ----
        const uint8_t* ar0 = At + (size_t)r0 * 128 + kg * 32;
        const uint8_t* br0 = Bt + (size_t)c0 * 128 + kg * 32;
        const uint8_t* ar1 = At + (size_t)r1 * 128 + kg * 32;
        const uint8_t* br1 = Bt + (size_t)c1 * 128 + kg * 32;
        uint4 la0 = *(const uint4*)(ar0);
        uint4 ha0 = *(const uint4*)(ar0 + 16);
        uint4 lb0 = *(const uint4*)(br0);
        uint4 hb0 = *(const uint4*)(br0 + 16);
        uint4 la1 = *(const uint4*)(ar1);
        uint4 ha1 = *(const uint4*)(ar1 + 16);
        uint4 lb1 = *(const uint4*)(br1);
        uint4 hb1 = *(const uint4*)(br1 + 16);

#pragma unroll
        for (int half = 0; half < 2; ++half) {
            int ebase = half ? ebase1 : ebase0;
            float attr = half ? attr1 : attr0;
            uint4 la = half ? la1 : la0, ha = half ? ha1 : ha0;
            uint4 lb = half ? lb1 : lb0, hb = half ? hb1 : hb0;

            // ---- layer 1: fp8 rows -> silu'd bf16 A-fragments ----
            short8 afrag[4];
#pragma unroll
            for (int kk = 0; kk < 4; ++kk) {
                int k0 = kk * 32 + kg * 8;
                uint32_t wa0 = (kk == 0) ? la.x : (kk == 1) ? la.z : (kk == 2) ? ha.x : ha.z;
                uint32_t wa1 = (kk == 0) ? la.y : (kk == 1) ? la.w : (kk == 2) ? ha.y : ha.w;
                uint32_t wb0 = (kk == 0) ? lb.x : (kk == 1) ? lb.z : (kk == 2) ? hb.x : hb.z;
                uint32_t wb1 = (kk == 0) ? lb.y : (kk == 1) ? lb.w : (kk == 2) ? hb.y : hb.w;
                float fa[8], fb[8];
                fp8_unpack8(wa0, wa1, fa);
                fp8_unpack8(wb0, wb1, fb);
                float xs[8];
#pragma unroll
                for (int j = 0; j < 8; ++j) {
                    xs[j] = fast_silu(fa[j] + fb[j] + attr * s_w1e[k0 + j]);
                }
                uint32_t* up = (uint32_t*)&afrag[kk];
                up[0] = cvt_pk_bf16(xs[0], xs[1]);
                up[1] = cvt_pk_bf16(xs[2], xs[3]);
                up[2] = cvt_pk_bf16(xs[4], xs[5]);
                up[3] = cvt_pk_bf16(xs[6], xs[7]);
            }

            // ---- layer 2 + fused silu + W3 dot (b2 folded into C) ----
            float pm0 = 0.f, pm1 = 0.f, pm2 = 0.f, pm3 = 0.f;
#pragma unroll
            for (int nt = 0; nt < 8; ++nt) {
                int n = nt * 16 + lrow;
                float b2v = s_b2[n];
                floatx4 acc = {b2v, b2v, b2v, b2v};
#pragma unroll
                for (int kk = 0; kk < 4; ++kk) {
                    int byte_off = (n << 8) + ((kk * 32 + kg * 8) << 1);
                    byte_off ^= ((n & 7) << 4);
                    short8 b = *(const short8*)((const char*)w2t + byte_off);
                    acc = __builtin_amdgcn_mfma_f32_16x16x32_bf16(afrag[kk], b, acc, 0, 0, 0);
                }
                float w3v = s_w3[n];
                pm0 += fast_silu(acc[0]) * w3v;
                pm1 += fast_silu(acc[1]) * w3v;
                pm2 += fast_silu(acc[2]) * w3v;
                pm3 += fast_silu(acc[3]) * w3v;
            }

            // reduce across the 16 lanes of each group
#pragma unroll
            for (int m = 1; m < 16; m <<= 1) {
                pm0 += __shfl_xor(pm0, m, 64);
                pm1 += __shfl_xor(pm1, m, 64);
                pm2 += __shfl_xor(pm2, m, 64);
                pm3 += __shfl_xor(pm3, m, 64);
            }
            // group kg holds m for edges ebase + kg*4 + {0..3} in pm0..pm3

            if (lrow < 12) {
                int rsel = lrow / 3;
                int dim = lrow - rsel * 3;
                float mval = (rsel == 0) ? pm0 : (rsel == 1) ? pm1
                           : (rsel == 2) ? pm2 : pm3;
                int eg = ebase + kg * 4 + rsel;
                float val = coord_diff[eg * 3 + dim] * mval * edge_mask[eg];
                int rnode = rowIdx[eg];
                atomicAdd(&agg[rnode * 3 + dim], val);
            }
        }
    }
}

// ---------------------------------------------------------------------------
// Kernel 3: out = (coord + agg/100) * node_mask
// ---------------------------------------------------------------------------
__global__ __launch_bounds__(256) void finalize_kernel(
    const float* __restrict__ coord, const float* __restrict__ agg,
    const float* __restrict__ node_mask, float* __restrict__ out)
{
    int i = blockIdx.x * 256 + threadIdx.x;
    if (i < N_NODES * 3) {
        out[i] = (coord[i] + agg[i] * 0.01f) * node_mask[i / 3];
    }
}

extern "C" void kernel_launch(void* const* d_in, const int* in_sizes, int n_in,
                              void* d_out, int out_size, void* d_ws, size_t ws_size,
                              hipStream_t stream) {
    const float* h          = (const float*)d_in[0];
    const float* coord      = (const float*)d_in[1];
    const int*   eidx       = (const int*)d_in[2];   // [2][N_EDGES] int32
    const float* coord_diff = (const float*)d_in[3];
    const float* edge_attr  = (const float*)d_in[4];
    const float* node_mask  = (const float*)d_in[5];
    const float* edge_mask  = (const float*)d_in[6];
    const float* W1 = (const float*)d_in[7];
    const float* b1 = (const float*)d_in[8];
    const float* W2 = (const float*)d_in[9];
    const float* b2 = (const float*)d_in[10];
    const float* W3 = (const float*)d_in[11];
    float* out = (float*)d_out;

    uint8_t* At = (uint8_t*)d_ws;                          // 6.4 MB
    uint8_t* Bt = At + (size_t)N_NODES * 128;              // 6.4 MB
    float*  agg = (float*)(Bt + (size_t)N_NODES * 128);    // 600 KB

    hipMemsetAsync(agg, 0, N_NODES * 3 * sizeof(float), stream);

    precompute_AB<<<(N_NODES + 127) / 128, 256, 0, stream>>>(h, W1, b1, At, Bt);

    edge_kernel<<<1024, 512, 0, stream>>>(eidx, eidx + N_EDGES, edge_attr, edge_mask,
                                          coord_diff, W1, W2, b2, W3, At, Bt, agg);

    finalize_kernel<<<(N_NODES * 3 + 255) / 256, 256, 0, stream>>>(coord, agg, node_mask, out);
}

// Round 10
// 161.120 us; speedup vs baseline: 1.3922x; 1.1076x over previous
//
#include <hip/hip_runtime.h>
#include <hip/hip_bf16.h>
#include <stdint.h>

#define N_NODES 50000
#define N_EDGES 1000000
#define HIDDEN 128

using short8  = __attribute__((ext_vector_type(8))) short;
using floatx4 = __attribute__((ext_vector_type(4))) float;
using floatx2 = __attribute__((ext_vector_type(2))) float;

__device__ __forceinline__ float bf2f(uint16_t u) {
    return __uint_as_float(((uint32_t)u) << 16);
}
__device__ __forceinline__ uint16_t f2bf(float f) {
    uint32_t x = __float_as_uint(f);
    return (uint16_t)((x + 0x7FFFu + ((x >> 16) & 1u)) >> 16);
}
__device__ __forceinline__ uint32_t cvt_pk_bf16(float lo, float hi) {
    uint32_t r;
    asm("v_cvt_pk_bf16_f32 %0, %1, %2" : "=v"(r) : "v"(lo), "v"(hi));
    return r;
}
__device__ __forceinline__ float fast_silu(float x) {
    float e = __expf(-x);
    return x * __builtin_amdgcn_rcpf(1.0f + e);
}
// one f32 -> one fp8 e4m3 byte (gfx950 OCP format)
__device__ __forceinline__ uint8_t f2fp8(float v) {
    uint32_t p = __builtin_amdgcn_cvt_pk_fp8_f32(v, v, 0u, false);
    return (uint8_t)(p & 0xffu);
}
// unpack 8 fp8 bytes (two u32 words) -> 8 f32
__device__ __forceinline__ void fp8_unpack8(uint32_t w0, uint32_t w1, float f[8]) {
    floatx2 p;
    p = __builtin_amdgcn_cvt_pk_f32_fp8(w0, false); f[0] = p[0]; f[1] = p[1];
    p = __builtin_amdgcn_cvt_pk_f32_fp8(w0, true);  f[2] = p[0]; f[3] = p[1];
    p = __builtin_amdgcn_cvt_pk_f32_fp8(w1, false); f[4] = p[0]; f[5] = p[1];
    p = __builtin_amdgcn_cvt_pk_f32_fp8(w1, true);  f[6] = p[0]; f[7] = p[1];
}

// channel permutation for At/Bt storage: c = kk*32 + kg*8 + j  ->  kg*32 + kk*8 + j
__device__ __forceinline__ int perm_c(int c) {
    return ((c >> 3) & 3) * 32 + ((c >> 5) << 3) + (c & 7);
}

// DPP rotate-add within each 16-lane row (pure VALU, no LDS pipe).
// ctrl must be a compile-time constant -> template parameter.
template <int CTRL>
__device__ __forceinline__ float row_ror_add(float v) {
    return v + __int_as_float(__builtin_amdgcn_update_dpp(
        0, __float_as_int(v), CTRL, 0xf, 0xf, false));
}
#define REDUCE16(v)                  \
    v = row_ror_add<0x121>(v);       \
    v = row_ror_add<0x122>(v);       \
    v = row_ror_add<0x124>(v);       \
    v = row_ror_add<0x128>(v);

// ---------------------------------------------------------------------------
// Kernel 1: At[n][k] = sum_j h[n][j]*W1[j][k] + b1[k]   (k<128)  -> fp8
//           Bt[n][k] = sum_j h[n][j]*W1[128+j][k]                -> fp8
// stored with perm_c channel order.
// ---------------------------------------------------------------------------
__global__ __launch_bounds__(256) void precompute_AB(
    const float* __restrict__ h, const float* __restrict__ W1,
    const float* __restrict__ b1,
    uint8_t* __restrict__ At, uint8_t* __restrict__ Bt)
{
    __shared__ uint16_t w1t[256 * 128];  // [c][j] bf16, XOR-swizzled, 64 KB
    int t = threadIdx.x;
    for (int idx = t; idx < 256 * 128; idx += 256) {
        int c = idx >> 7, j = idx & 127;
        float v = (c < 128) ? W1[j * 128 + c] : W1[(128 + j) * 128 + (c - 128)];
        int byte_off = (c << 8) + (j << 1);
        byte_off ^= ((c & 7) << 4);
        *(uint16_t*)((char*)w1t + byte_off) = f2bf(v);
    }
    __syncthreads();

    int wave = t >> 6, lane = t & 63;
    int lrow = lane & 15, kg = lane >> 4;

    for (int g = 0; g < 2; ++g) {
        int nodeBase = blockIdx.x * 128 + g * 64 + wave * 16;
        if (nodeBase >= N_NODES) break;
        int node = nodeBase + lrow;
        int nclamp = node < N_NODES ? node : N_NODES - 1;
        const float* hrow = h + (size_t)nclamp * 128;

        short8 afrag[4];
#pragma unroll
        for (int kk = 0; kk < 4; ++kk) {
            int k0 = kk * 32 + kg * 8;
            float4 f0 = *(const float4*)(hrow + k0);
            float4 f1 = *(const float4*)(hrow + k0 + 4);
            short8 a;
            uint32_t* ap = (uint32_t*)&a;
            ap[0] = cvt_pk_bf16(f0.x, f0.y);
            ap[1] = cvt_pk_bf16(f0.z, f0.w);
            ap[2] = cvt_pk_bf16(f1.x, f1.y);
            ap[3] = cvt_pk_bf16(f1.z, f1.w);
            afrag[kk] = a;
        }

        for (int nt = 0; nt < 16; ++nt) {
            floatx4 acc = {0.f, 0.f, 0.f, 0.f};
            int c = nt * 16 + lrow;
#pragma unroll
            for (int kk = 0; kk < 4; ++kk) {
                int byte_off = (c << 8) + ((kk * 32 + kg * 8) << 1);
                byte_off ^= ((c & 7) << 4);
                short8 b = *(const short8*)((const char*)w1t + byte_off);
                acc = __builtin_amdgcn_mfma_f32_16x16x32_bf16(afrag[kk], b, acc, 0, 0, 0);
            }
#pragma unroll
            for (int r = 0; r < 4; ++r) {
                int onode = nodeBase + kg * 4 + r;
                if (onode < N_NODES) {
                    float v = acc[r];
                    if (c < 128) {
                        At[(size_t)onode * 128 + perm_c(c)] = f2fp8(v + b1[c]);
                    } else {
                        int cc = c - 128;
                        Bt[(size_t)onode * 128 + perm_c(cc)] = f2fp8(v);
                    }
                }
            }
        }
    }
}

// ---------------------------------------------------------------------------
// Kernel 2: per-edge fused MLP. 512-thr blocks, one wave = 32 edges.
// w2t stored LANE-LINEAR per MFMA-read: element ((nt*4+kk)*64 + lane)*8 + j
// holds W2[k=kk*32+(lane>>4)*8+j][n=nt*16+(lane&15)] -> every ds_read_b128
// in the hot loop is stride-1 across lanes (zero bank conflicts by
// construction; the old XOR layout had ~8-way: 8M conflict-cycles/dispatch).
// 16-lane reduce via DPP row_ror adds (VALU) instead of __shfl_xor (LDS).
// VGPR must stay <=64 (8 waves/SIMD; crossing 64 halves occupancy, round 7).
// ---------------------------------------------------------------------------
__global__ __launch_bounds__(512) void edge_kernel(
    const int* __restrict__ rowIdx, const int* __restrict__ colIdx,
    const float* __restrict__ edge_attr, const float* __restrict__ edge_mask,
    const float* __restrict__ coord_diff,
    const float* __restrict__ W1, const float* __restrict__ W2,
    const float* __restrict__ b2, const float* __restrict__ W3,
    const uint8_t* __restrict__ At, const uint8_t* __restrict__ Bt,
    float* __restrict__ agg)
{
    __shared__ uint16_t w2t[128 * 128];  // [nt][kk][lane][8] bf16, 32 KB
    __shared__ float s_w1e[128], s_b2[128], s_w3[128];
    int t = threadIdx.x;
    for (int idx = t; idx < 128 * 128; idx += 512) {
        int j    = idx & 7;
        int ln   = (idx >> 3) & 63;
        int kkq  = (idx >> 9) & 3;
        int ntq  = idx >> 11;
        int n = ntq * 16 + (ln & 15);
        int k = kkq * 32 + (ln >> 4) * 8 + j;
        w2t[idx] = f2bf(W2[k * 128 + n]);
    }
    if (t < 128) { s_w1e[t] = W1[256 * 128 + t]; s_b2[t] = b2[t]; s_w3[t] = W3[t]; }
    __syncthreads();

    int wave = t >> 6, lane = t & 63;
    int lrow = lane & 15, kg = lane >> 4;

    const int numPairs = N_EDGES / 32;           // 31250
    int wavesTotal = gridDim.x * 8;
    int waveId = blockIdx.x * 8 + wave;

    for (int pair = waveId; pair < numPairs; pair += wavesTotal) {
        int ebase0 = pair * 32;
        int ebase1 = ebase0 + 16;
        int e0 = ebase0 + lrow;
        int e1 = ebase1 + lrow;
        int r0 = rowIdx[e0], c0 = colIdx[e0];
        int r1 = rowIdx[e1], c1 = colIdx[e1];
        float attr0 = edge_attr[e0];
        float attr1 = edge_attr[e1];

        // ---- all 8 gathers up front (half-0 first) ----
        const uint8_t* ar0 = At + (size_t)r0 * 128 + kg * 32;
        const uint8_t* br0 = Bt + (size_t)c0 * 128 + kg * 32;
        const uint8_t* ar1 = At + (size_t)r1 * 128 + kg * 32;
        const uint8_t* br1 = Bt + (size_t)c1 * 128 + kg * 32;
        uint4 la0 = *(const uint4*)(ar0);
        uint4 ha0 = *(const uint4*)(ar0 + 16);
        uint4 lb0 = *(const uint4*)(br0);
        uint4 hb0 = *(const uint4*)(br0 + 16);
        uint4 la1 = *(const uint4*)(ar1);
        uint4 ha1 = *(const uint4*)(ar1 + 16);
        uint4 lb1 = *(const uint4*)(br1);
        uint4 hb1 = *(const uint4*)(br1 + 16);

#pragma unroll
        for (int half = 0; half < 2; ++half) {
            int ebase = half ? ebase1 : ebase0;
            float attr = half ? attr1 : attr0;
            uint4 la = half ? la1 : la0, ha = half ? ha1 : ha0;
            uint4 lb = half ? lb1 : lb0, hb = half ? hb1 : hb0;

            // ---- layer 1: fp8 rows -> silu'd bf16 A-fragments ----
            short8 afrag[4];
#pragma unroll
            for (int kk = 0; kk < 4; ++kk) {
                int k0 = kk * 32 + kg * 8;
                uint32_t wa0 = (kk == 0) ? la.x : (kk == 1) ? la.z : (kk == 2) ? ha.x : ha.z;
                uint32_t wa1 = (kk == 0) ? la.y : (kk == 1) ? la.w : (kk == 2) ? ha.y : ha.w;
                uint32_t wb0 = (kk == 0) ? lb.x : (kk == 1) ? lb.z : (kk == 2) ? hb.x : hb.z;
                uint32_t wb1 = (kk == 0) ? lb.y : (kk == 1) ? lb.w : (kk == 2) ? hb.y : hb.w;
                float fa[8], fb[8];
                fp8_unpack8(wa0, wa1, fa);
                fp8_unpack8(wb0, wb1, fb);
                float xs[8];
#pragma unroll
                for (int j = 0; j < 8; ++j) {
                    xs[j] = fast_silu(fa[j] + fb[j] + attr * s_w1e[k0 + j]);
                }
                uint32_t* up = (uint32_t*)&afrag[kk];
                up[0] = cvt_pk_bf16(xs[0], xs[1]);
                up[1] = cvt_pk_bf16(xs[2], xs[3]);
                up[2] = cvt_pk_bf16(xs[4], xs[5]);
                up[3] = cvt_pk_bf16(xs[6], xs[7]);
            }

            // ---- layer 2 + fused silu + W3 dot (b2 folded into C) ----
            float pm0 = 0.f, pm1 = 0.f, pm2 = 0.f, pm3 = 0.f;
#pragma unroll
            for (int nt = 0; nt < 8; ++nt) {
                int n = nt * 16 + lrow;
                float b2v = s_b2[n];
                floatx4 acc = {b2v, b2v, b2v, b2v};
#pragma unroll
                for (int kk = 0; kk < 4; ++kk) {
                    const short8* bp = (const short8*)(w2t + (((nt * 4 + kk) * 64 + lane) << 3));
                    acc = __builtin_amdgcn_mfma_f32_16x16x32_bf16(afrag[kk], *bp, acc, 0, 0, 0);
                }
                float w3v = s_w3[n];
                pm0 += fast_silu(acc[0]) * w3v;
                pm1 += fast_silu(acc[1]) * w3v;
                pm2 += fast_silu(acc[2]) * w3v;
                pm3 += fast_silu(acc[3]) * w3v;
            }

            // rotate-reduce across the 16-lane row (DPP, pure VALU)
            REDUCE16(pm0);
            REDUCE16(pm1);
            REDUCE16(pm2);
            REDUCE16(pm3);
            // group kg holds m for edges ebase + kg*4 + {0..3} in pm0..pm3

            if (lrow < 12) {
                int rsel = lrow / 3;
                int dim = lrow - rsel * 3;
                float mval = (rsel == 0) ? pm0 : (rsel == 1) ? pm1
                           : (rsel == 2) ? pm2 : pm3;
                int eg = ebase + kg * 4 + rsel;
                float val = coord_diff[eg * 3 + dim] * mval * edge_mask[eg];
                int rnode = rowIdx[eg];
                atomicAdd(&agg[rnode * 3 + dim], val);
            }
        }
    }
}

// ---------------------------------------------------------------------------
// Kernel 3: out = (coord + agg/100) * node_mask
// ---------------------------------------------------------------------------
__global__ __launch_bounds__(256) void finalize_kernel(
    const float* __restrict__ coord, const float* __restrict__ agg,
    const float* __restrict__ node_mask, float* __restrict__ out)
{
    int i = blockIdx.x * 256 + threadIdx.x;
    if (i < N_NODES * 3) {
        out[i] = (coord[i] + agg[i] * 0.01f) * node_mask[i / 3];
    }
}

extern "C" void kernel_launch(void* const* d_in, const int* in_sizes, int n_in,
                              void* d_out, int out_size, void* d_ws, size_t ws_size,
                              hipStream_t stream) {
    const float* h          = (const float*)d_in[0];
    const float* coord      = (const float*)d_in[1];
    const int*   eidx       = (const int*)d_in[2];   // [2][N_EDGES] int32
    const float* coord_diff = (const float*)d_in[3];
    const float* edge_attr  = (const float*)d_in[4];
    const float* node_mask  = (const float*)d_in[5];
    const float* edge_mask  = (const float*)d_in[6];
    const float* W1 = (const float*)d_in[7];
    const float* b1 = (const float*)d_in[8];
    const float* W2 = (const float*)d_in[9];
    const float* b2 = (const float*)d_in[10];
    const float* W3 = (const float*)d_in[11];
    float* out = (float*)d_out;

    uint8_t* At = (uint8_t*)d_ws;                          // 6.4 MB
    uint8_t* Bt = At + (size_t)N_NODES * 128;              // 6.4 MB
    float*  agg = (float*)(Bt + (size_t)N_NODES * 128);    // 600 KB

    hipMemsetAsync(agg, 0, N_NODES * 3 * sizeof(float), stream);

    precompute_AB<<<(N_NODES + 127) / 128, 256, 0, stream>>>(h, W1, b1, At, Bt);

    edge_kernel<<<1024, 512, 0, stream>>>(eidx, eidx + N_EDGES, edge_attr, edge_mask,
                                          coord_diff, W1, W2, b2, W3, At, Bt, agg);

    finalize_kernel<<<(N_NODES * 3 + 255) / 256, 256, 0, stream>>>(coord, agg, node_mask, out);
}